// Round 7
// baseline (652.854 us; speedup 1.0000x reference)
//
#include <hip/hip_runtime.h>
#include <hip/hip_bf16.h>
#include <stdint.h>

#define M_DIM 8192
#define N_DIM 4096
#define K_DIM 4096
#define NNZ   1600000

typedef __attribute__((ext_vector_type(8))) short bf16x8;
typedef __attribute__((ext_vector_type(4))) float f32x4;

// workspace layout (bytes)
static const size_t WF32_OFF  = 0;
static const size_t WBF16_OFF = 64ull << 20;
static const size_t XB_OFF    = 96ull << 20;
static const size_t WS_NEED   = 160ull << 20;

__device__ __forceinline__ unsigned short f2bf(float f) {
    union { float f; uint32_t u; } a; a.f = f;
    uint32_t u = a.u;
    uint32_t r = (u + 0x7FFFu + ((u >> 16) & 1u)) >> 16;   // RNE
    return (unsigned short)r;
}

__global__ void scatter_kernel(const int* __restrict__ idx,
                               const float* __restrict__ vals,
                               float* __restrict__ W) {
    int t = blockIdx.x * blockDim.x + threadIdx.x;
    if (t < NNZ) {
        int2 rc = ((const int2*)idx)[t];
        atomicAdd(&W[(size_t)rc.x * K_DIM + rc.y], vals[t]);
    }
}

__global__ void f32_to_bf16_kernel(const float* __restrict__ src,
                                   unsigned short* __restrict__ dst, int n4) {
    int t = blockIdx.x * blockDim.x + threadIdx.x;
    if (t < n4) {
        float4 v = ((const float4*)src)[t];
        ushort4 o;
        o.x = f2bf(v.x); o.y = f2bf(v.y); o.z = f2bf(v.z); o.w = f2bf(v.w);
        ((ushort4*)dst)[t] = o;
    }
}

// ---------------------------------------------------------------------------
// 256x256 bf16 MFMA GEMM, BK=64, 8 waves (2Mx4N), per-wave 128x64 out,
// 16x16x32 MFMA (the verified conflict-free fragment pattern; r6 proved the
// 32x32 pattern 4-way-conflicts with this swizzle).
// READ-AHEAD pipeline: each phase issues the ds_reads for the NEXT MFMA
// cluster, so every read has a full cluster (~600 cyc) to complete:
//   quadrant order Q00(aLo,bLo) -> Q01(aLo,bHi) -> Q11(aHi,bHi) -> Q10(aHi,bLo)
//   ph0: read bHi(4)            | BAR | Q00 |
//   ph1: read aHi(8)            | BAR | Q01 |              [aLo dead]
//   ph2:                          BAR | Q11 | stage A(t+2) [bHi dead]
//   ph3: vmcnt(4); read aLo',bLo' of t+1 (12) | BAR | Q10 | stage B(t+2)
// vmcnt(4) drains A(t+1),B(t+1) (t+1 valid for ph3's reads), keeps A(t+2)
// in flight — never 0 until the tail. 4 barriers/tile.
// Stage safety: A(t+2)@ph2 is >=1 BAR + 1 cluster after last A-read issue
// (aHi@ph1); B(t+2)@ph3 is 3 BARs after last B-read issue (bHi@ph0).
// LDS swizzle (0-conflict, measured r1-r5): 16B slot u of row r at u^(r&7);
// inverse-swizzled global source keeps gload_lds dest linear (rule 21).
// ---------------------------------------------------------------------------
#define GLOAD16(gp, lp) __builtin_amdgcn_global_load_lds( \
    (const __attribute__((address_space(1))) void*)(gp),  \
    (__attribute__((address_space(3))) void*)(lp), 16, 0, 0)
#define VMCNT(n)   asm volatile("s_waitcnt vmcnt(" #n ")" ::: "memory")
#define BAR()    __builtin_amdgcn_s_barrier()

// frag read from 256x64 swizzled tile: row r, k-slot kk in {0,1}
#define FRAG(T, r, kk) \
    (*(const bf16x8*)&(T)[(r) * 64 + (((((kk) << 2) + l4) ^ ((r) & 7)) << 3)])

// stage one 64-row group g (0..3) of a 256x64 tile: 1 gload x 512 thr x 16B
#define STAGE_AG(buf, tt, g) \
    GLOAD16(Ab + (size_t)((g) * 64 + rbase) * K_DIM + (size_t)(tt) * 64 + cs, \
            &sA[buf][(g) * 4096 + wid * 512])
#define STAGE_BG(buf, tt, g) \
    GLOAD16(Bb + (size_t)((g) * 64 + rbase) * K_DIM + (size_t)(tt) * 64 + cs, \
            &sB[buf][(g) * 4096 + wid * 512])

#define MFMA16(ACC, AF, BF)                                                   \
    _Pragma("unroll")                                                         \
    for (int k = 0; k < 2; ++k)                                               \
        _Pragma("unroll")                                                     \
        for (int m = 0; m < 4; ++m)                                           \
            _Pragma("unroll")                                                 \
            for (int n = 0; n < 2; ++n)                                       \
                ACC[m][n] = __builtin_amdgcn_mfma_f32_16x16x32_bf16(          \
                                AF[m][k], BF[n][k], ACC[m][n], 0, 0, 0)

__global__ __launch_bounds__(512, 2) void gemm256_v7(
        const __hip_bfloat16* __restrict__ A,   // M x K
        const __hip_bfloat16* __restrict__ B,   // N x K
        float* __restrict__ C)                  // M x N
{
    __shared__ __align__(16) __hip_bfloat16 sA[2][256 * 64];
    __shared__ __align__(16) __hip_bfloat16 sB[2][256 * 64];

    const int tid  = threadIdx.x;
    const int lane = tid & 63;
    const int wid  = tid >> 6;
    const int wr   = wid >> 2;      // 0..1  (128-row half of A-tile)
    const int wc   = wid & 3;       // 0..3  (64-col slice of B-tile)
    const int l15  = lane & 15, l4 = lane >> 4;

    // XCD-aware bijective swizzle (nwg = 512, %8 == 0)
    const int bid = blockIdx.x;
    const int swz = (bid & 7) * 64 + (bid >> 3);
    const int m0  = (swz >> 4) * 256;   // 32 m-tiles
    const int n0  = (swz & 15) * 256;   // 16 n-tiles

    // staging geometry: row-in-group = tid>>3; 16B col-slot u = tid&7;
    // inverse-swizzled source col = (u ^ (row&7))*8
    const int rbase = tid >> 3;
    const int cs    = ((tid & 7) ^ (rbase & 7)) << 3;

    const __hip_bfloat16* Ab = A + (size_t)m0 * K_DIM;
    const __hip_bfloat16* Bb = B + (size_t)n0 * K_DIM;

    // acc quadrants: [m 0..3]=mLo rows, [m 4..7]=mHi; [n 0..1]=nLo, [2..3]=nHi
    f32x4 acc[8][4] = {};

    // ---- prologue: stage tile0 + tile1 fully (16 loads) ----
    STAGE_AG(0, 0, 0); STAGE_AG(0, 0, 1); STAGE_AG(0, 0, 2); STAGE_AG(0, 0, 3);
    STAGE_BG(0, 0, 0); STAGE_BG(0, 0, 1); STAGE_BG(0, 0, 2); STAGE_BG(0, 0, 3);
    STAGE_AG(1, 1, 0); STAGE_AG(1, 1, 1); STAGE_AG(1, 1, 2); STAGE_AG(1, 1, 3);
    STAGE_BG(1, 1, 0); STAGE_BG(1, 1, 1); STAGE_BG(1, 1, 2); STAGE_BG(1, 1, 3);
    VMCNT(8);          // tile 0 landed; tile 1 (A,B) in flight
    BAR();

    // initial read-ahead: aLo, bLo of tile 0
    bf16x8 aLo[4][2], bLo[2][2];
    #pragma unroll
    for (int m = 0; m < 4; ++m) {
        const int r = wr * 128 + m * 16 + l15;
        aLo[m][0] = FRAG(sA[0], r, 0);
        aLo[m][1] = FRAG(sA[0], r, 1);
    }
    #pragma unroll
    for (int n = 0; n < 2; ++n) {
        const int r = wc * 64 + n * 16 + l15;
        bLo[n][0] = FRAG(sB[0], r, 0);
        bLo[n][1] = FRAG(sB[0], r, 1);
    }

    const int NT = K_DIM / 64;      // 64
    #pragma unroll 2
    for (int t = 0; t < NT; ++t) {
        const int c = t & 1;
        const __hip_bfloat16* TA  = sA[c];
        const __hip_bfloat16* TB  = sB[c];
        const __hip_bfloat16* TAn = sA[c ^ 1];
        const __hip_bfloat16* TBn = sB[c ^ 1];

        bf16x8 aHi[4][2], bHi[2][2], aLoN[4][2], bLoN[2][2];

        // ---------- ph0: read bHi | BAR | Q00 = aLo x bLo ----------
        #pragma unroll
        for (int n = 0; n < 2; ++n) {
            const int r = wc * 64 + 32 + n * 16 + l15;
            bHi[n][0] = FRAG(TB, r, 0);
            bHi[n][1] = FRAG(TB, r, 1);
        }
        BAR();
        __builtin_amdgcn_s_setprio(1);
        #pragma unroll
        for (int k = 0; k < 2; ++k)
            #pragma unroll
            for (int m = 0; m < 4; ++m)
                #pragma unroll
                for (int n = 0; n < 2; ++n)
                    acc[m][n] = __builtin_amdgcn_mfma_f32_16x16x32_bf16(
                                    aLo[m][k], bLo[n][k], acc[m][n], 0, 0, 0);
        __builtin_amdgcn_s_setprio(0);

        // ---------- ph1: read aHi | BAR | Q01 = aLo x bHi ----------
        #pragma unroll
        for (int m = 0; m < 4; ++m) {
            const int r = wr * 128 + 64 + m * 16 + l15;
            aHi[m][0] = FRAG(TA, r, 0);
            aHi[m][1] = FRAG(TA, r, 1);
        }
        BAR();
        __builtin_amdgcn_s_setprio(1);
        #pragma unroll
        for (int k = 0; k < 2; ++k)
            #pragma unroll
            for (int m = 0; m < 4; ++m)
                #pragma unroll
                for (int n = 0; n < 2; ++n)
                    acc[m][2 + n] = __builtin_amdgcn_mfma_f32_16x16x32_bf16(
                                    aLo[m][k], bHi[n][k], acc[m][2 + n], 0, 0, 0);
        __builtin_amdgcn_s_setprio(0);

        // ---------- ph2: BAR | Q11 = aHi x bHi | stage A(t+2) ----------
        BAR();
        __builtin_amdgcn_s_setprio(1);
        #pragma unroll
        for (int k = 0; k < 2; ++k)
            #pragma unroll
            for (int m = 0; m < 4; ++m)
                #pragma unroll
                for (int n = 0; n < 2; ++n)
                    acc[4 + m][2 + n] = __builtin_amdgcn_mfma_f32_16x16x32_bf16(
                                    aHi[m][k], bHi[n][k], acc[4 + m][2 + n], 0, 0, 0);
        __builtin_amdgcn_s_setprio(0);
        if (t + 2 < NT) {
            STAGE_AG(c, t + 2, 0); STAGE_AG(c, t + 2, 1);
            STAGE_AG(c, t + 2, 2); STAGE_AG(c, t + 2, 3);
        }

        // ---------- ph3: vmcnt; read aLo',bLo' of t+1 | BAR | Q10 | stage B(t+2)
        if (t + 1 < NT) {
            if (t + 2 < NT) { VMCNT(4); } else { VMCNT(0); }
            #pragma unroll
            for (int m = 0; m < 4; ++m) {
                const int r = wr * 128 + m * 16 + l15;
                aLoN[m][0] = FRAG(TAn, r, 0);
                aLoN[m][1] = FRAG(TAn, r, 1);
            }
            #pragma unroll
            for (int n = 0; n < 2; ++n) {
                const int r = wc * 64 + n * 16 + l15;
                bLoN[n][0] = FRAG(TBn, r, 0);
                bLoN[n][1] = FRAG(TBn, r, 1);
            }
        }
        BAR();
        __builtin_amdgcn_s_setprio(1);
        #pragma unroll
        for (int k = 0; k < 2; ++k)
            #pragma unroll
            for (int m = 0; m < 4; ++m)
                #pragma unroll
                for (int n = 0; n < 2; ++n)
                    acc[4 + m][n] = __builtin_amdgcn_mfma_f32_16x16x32_bf16(
                                    aHi[m][k], bLo[n][k], acc[4 + m][n], 0, 0, 0);
        __builtin_amdgcn_s_setprio(0);
        if (t + 2 < NT) { STAGE_BG(c, t + 2, 0); STAGE_BG(c, t + 2, 1);
                          STAGE_BG(c, t + 2, 2); STAGE_BG(c, t + 2, 3); }

        // rotate read-ahead regs (renamed away by unroll-2)
        if (t + 1 < NT) {
            #pragma unroll
            for (int m = 0; m < 4; ++m) { aLo[m][0] = aLoN[m][0]; aLo[m][1] = aLoN[m][1]; }
            #pragma unroll
            for (int n = 0; n < 2; ++n) { bLo[n][0] = bLoN[n][0]; bLo[n][1] = bLoN[n][1]; }
        }
    }

    // ---- epilogue: ReLU + fp32 store ----
    const int row_base = m0 + wr * 128;
    const int col_base = n0 + wc * 64;
    #pragma unroll
    for (int m = 0; m < 8; ++m)
        #pragma unroll
        for (int n = 0; n < 4; ++n) {
            const f32x4 v = acc[m][n];
            const int col = col_base + n * 16 + l15;
            #pragma unroll
            for (int j = 0; j < 4; ++j) {
                const int row = row_base + m * 16 + l4 * 4 + j;
                C[(size_t)row * N_DIM + col] = fmaxf(v[j], 0.0f);
            }
        }
}

// ---------------------------------------------------------------------------
// fp32 fallback GEMM (only if ws_size < 160MB)
// ---------------------------------------------------------------------------
__global__ void gemm_f32_fallback(const float* __restrict__ A,
                                  const float* __restrict__ W,
                                  float* __restrict__ C) {
    __shared__ float As[64][17];
    __shared__ float Bs[64][17];
    const int tx = threadIdx.x & 15, ty = threadIdx.x >> 4;
    const int m0 = blockIdx.y * 64, n0 = blockIdx.x * 64;
    float acc[4][4] = {};
    for (int kt = 0; kt < K_DIM; kt += 16) {
        #pragma unroll
        for (int i = 0; i < 4; ++i) {
            int e = threadIdx.x + i * 256;
            int r = e >> 4, k = e & 15;
            As[r][k] = A[(size_t)(m0 + r) * K_DIM + kt + k];
            Bs[r][k] = W[(size_t)(n0 + r) * K_DIM + kt + k];
        }
        __syncthreads();
        #pragma unroll
        for (int k = 0; k < 16; ++k) {
            float av[4], bv[4];
            #pragma unroll
            for (int i = 0; i < 4; ++i) av[i] = As[ty * 4 + i][k];
            #pragma unroll
            for (int i = 0; i < 4; ++i) bv[i] = Bs[tx * 4 + i][k];
            #pragma unroll
            for (int i = 0; i < 4; ++i)
                #pragma unroll
                for (int j = 0; j < 4; ++j) acc[i][j] += av[i] * bv[j];
        }
        __syncthreads();
    }
    #pragma unroll
    for (int i = 0; i < 4; ++i)
        #pragma unroll
        for (int j = 0; j < 4; ++j)
            C[(size_t)(m0 + ty * 4 + i) * N_DIM + n0 + tx * 4 + j] =
                fmaxf(acc[i][j], 0.0f);
}

extern "C" void kernel_launch(void* const* d_in, const int* in_sizes, int n_in,
                              void* d_out, int out_size, void* d_ws, size_t ws_size,
                              hipStream_t stream) {
    const float* x       = (const float*)d_in[0];
    const int*   indices = (const int*)d_in[1];
    const float* values  = (const float*)d_in[2];
    float*       out     = (float*)d_out;

    float* Wf = (float*)((char*)d_ws + WF32_OFF);

    // 1. zero + scatter-build W (fp32, duplicates accumulate)
    hipMemsetAsync(Wf, 0, (size_t)N_DIM * K_DIM * sizeof(float), stream);
    scatter_kernel<<<(NNZ + 255) / 256, 256, 0, stream>>>(indices, values, Wf);

    if (ws_size >= WS_NEED) {
        unsigned short* Wb = (unsigned short*)((char*)d_ws + WBF16_OFF);
        unsigned short* xb = (unsigned short*)((char*)d_ws + XB_OFF);

        // 2. fp32 -> bf16 conversions
        {
            int n4 = (N_DIM * K_DIM) / 4;
            f32_to_bf16_kernel<<<(n4 + 255) / 256, 256, 0, stream>>>(Wf, Wb, n4);
        }
        {
            int n4 = (M_DIM * K_DIM) / 4;
            f32_to_bf16_kernel<<<(n4 + 255) / 256, 256, 0, stream>>>(x, xb, n4);
        }

        // 3. 256^2 read-ahead 16x16x32 bf16 MFMA GEMM + ReLU
        gemm256_v7<<<(M_DIM / 256) * (N_DIM / 256), 512, 0, stream>>>(
            (const __hip_bfloat16*)xb, (const __hip_bfloat16*)Wb, out);
    } else {
        gemm_f32_fallback<<<dim3(N_DIM / 64, M_DIM / 64), 256, 0, stream>>>(
            x, Wf, out);
    }
}

// Round 8
// 363.214 us; speedup vs baseline: 1.7974x; 1.7974x over previous
//
#include <hip/hip_runtime.h>
#include <hip/hip_bf16.h>
#include <stdint.h>

#define M_DIM 8192
#define N_DIM 4096
#define K_DIM 4096
#define NNZ   1600000

typedef __attribute__((ext_vector_type(8))) short bf16x8;
typedef __attribute__((ext_vector_type(4))) float f32x4;

// workspace layout (bytes)
static const size_t WF32_OFF  = 0;
static const size_t WBF16_OFF = 64ull << 20;
static const size_t XB_OFF    = 96ull << 20;
static const size_t WS_NEED   = 160ull << 20;

__device__ __forceinline__ unsigned short f2bf(float f) {
    union { float f; uint32_t u; } a; a.f = f;
    uint32_t u = a.u;
    uint32_t r = (u + 0x7FFFu + ((u >> 16) & 1u)) >> 16;   // RNE
    return (unsigned short)r;
}

__global__ void scatter_kernel(const int* __restrict__ idx,
                               const float* __restrict__ vals,
                               float* __restrict__ W) {
    int t = blockIdx.x * blockDim.x + threadIdx.x;
    if (t < NNZ) {
        int2 rc = ((const int2*)idx)[t];
        atomicAdd(&W[(size_t)rc.x * K_DIM + rc.y], vals[t]);
    }
}

// one kernel converts BOTH W (n4W quads) and x (n4X quads) fp32 -> bf16
__global__ void convert_both_kernel(const float* __restrict__ W,
                                    const float* __restrict__ x,
                                    unsigned short* __restrict__ Wb,
                                    unsigned short* __restrict__ xb,
                                    int n4W, int n4T) {
    int t = blockIdx.x * blockDim.x + threadIdx.x;
    if (t >= n4T) return;
    const float* src; unsigned short* dst; int i;
    if (t < n4W) { src = W; dst = Wb; i = t; }
    else         { src = x; dst = xb; i = t - n4W; }
    float4 v = ((const float4*)src)[i];
    ushort4 o;
    o.x = f2bf(v.x); o.y = f2bf(v.y); o.z = f2bf(v.z); o.w = f2bf(v.w);
    ((ushort4*)dst)[i] = o;
}

// ---------------------------------------------------------------------------
// 256x256 bf16 MFMA GEMM, BK=64, 8 waves (2Mx4N), per-wave 128x64 out,
// 16x16x32 MFMA. THREE barriers per K-tile (only the WAR-required ones):
//   R0: read aLo(8)+bLo(4) ; MFMA Q00 ; stage B(t+1)g23 ; read aHi(8)
//   BAR_A   (all A-reads + bLo reads of buf c done)
//   R1: stage A(t+2)->c ; MFMA Q10 ; read bHi(4)
//   BAR_B   (all B-reads of buf c done)
//   R2: stage B(t+2)g01->c ; MFMA Q11 ; MFMA Q01 ; vmcnt(6) ; BAR
// vmcnt(6) at boundary drains all of tile t+1 (oldest 8 of 14 outstanding),
// keeps A(t+2)x4 + B(t+2)g01x2 in flight. Never 0 until the tail.
// Stage-fence proof (byte-level, incl. wc>=2 bLo rows in g2/g3):
//   B(t+1)g23 region last read during t-1's R1 (bHi) -> >= 2 barriers margin.
//   A(t+2) into c: last A-read = aHi in R0, fenced by BAR_A.
//   B(t+2)g01 into c: last B-read = bHi in R1, fenced by BAR_B.
// LDS swizzle (0-conflict, measured r1-r5): 16B slot u of row r at u^(r&7);
// inverse-swizzled global source keeps gload_lds dest linear (rule 21).
// Register budget: frags 96 VGPR + acc 128 AGPR (peak ~224) — no liveness
// across the boundary (r7 lesson: +48 regs => spill).
// ---------------------------------------------------------------------------
#define GLOAD16(gp, lp) __builtin_amdgcn_global_load_lds( \
    (const __attribute__((address_space(1))) void*)(gp),  \
    (__attribute__((address_space(3))) void*)(lp), 16, 0, 0)
#define VMCNT(n)   asm volatile("s_waitcnt vmcnt(" #n ")" ::: "memory")
#define BAR()    __builtin_amdgcn_s_barrier()

// frag read from 256x64 swizzled tile: row r, k-slot kk in {0,1}
#define FRAG(T, r, kk) \
    (*(const bf16x8*)&(T)[(r) * 64 + (((((kk) << 2) + l4) ^ ((r) & 7)) << 3)])

// stage one 64-row group g (0..3) of a 256x64 tile: 1 gload x 512 thr x 16B
#define STAGE_AG(buf, tt, g) \
    GLOAD16(Ab + (size_t)((g) * 64 + rbase) * K_DIM + (size_t)(tt) * 64 + cs, \
            &sA[buf][(g) * 4096 + wid * 512])
#define STAGE_BG(buf, tt, g) \
    GLOAD16(Bb + (size_t)((g) * 64 + rbase) * K_DIM + (size_t)(tt) * 64 + cs, \
            &sB[buf][(g) * 4096 + wid * 512])

__global__ __launch_bounds__(512, 2) void gemm256_v8(
        const __hip_bfloat16* __restrict__ A,   // M x K
        const __hip_bfloat16* __restrict__ B,   // N x K
        float* __restrict__ C)                  // M x N
{
    __shared__ __align__(16) __hip_bfloat16 sA[2][256 * 64];
    __shared__ __align__(16) __hip_bfloat16 sB[2][256 * 64];

    const int tid  = threadIdx.x;
    const int lane = tid & 63;
    const int wid  = tid >> 6;
    const int wr   = wid >> 2;      // 0..1  (128-row half of A-tile)
    const int wc   = wid & 3;       // 0..3  (64-col slice of B-tile)
    const int l15  = lane & 15, l4 = lane >> 4;

    // XCD-aware bijective swizzle (nwg = 512, %8 == 0)
    const int bid = blockIdx.x;
    const int swz = (bid & 7) * 64 + (bid >> 3);
    const int m0  = (swz >> 4) * 256;   // 32 m-tiles
    const int n0  = (swz & 15) * 256;   // 16 n-tiles

    // staging geometry: row-in-group = tid>>3; 16B col-slot u = tid&7;
    // inverse-swizzled source col = (u ^ (row&7))*8
    const int rbase = tid >> 3;
    const int cs    = ((tid & 7) ^ (rbase & 7)) << 3;

    const __hip_bfloat16* Ab = A + (size_t)m0 * K_DIM;
    const __hip_bfloat16* Bb = B + (size_t)n0 * K_DIM;

    // acc quadrants: m 0..3 = mLo, 4..7 = mHi; n 0..1 = nLo, 2..3 = nHi
    f32x4 acc[8][4] = {};

    // ---- prologue: tile0 full (8), A(1) full (4), B(1) g0,g1 (2) ----
    STAGE_AG(0, 0, 0); STAGE_AG(0, 0, 1); STAGE_AG(0, 0, 2); STAGE_AG(0, 0, 3);
    STAGE_BG(0, 0, 0); STAGE_BG(0, 0, 1); STAGE_BG(0, 0, 2); STAGE_BG(0, 0, 3);
    STAGE_AG(1, 1, 0); STAGE_AG(1, 1, 1); STAGE_AG(1, 1, 2); STAGE_AG(1, 1, 3);
    STAGE_BG(1, 1, 0); STAGE_BG(1, 1, 1);
    VMCNT(6);          // tile 0 landed; {A(1) x4, B(1)g01 x2} in flight
    BAR();

    const int NT = K_DIM / 64;      // 64
    #pragma unroll 2
    for (int t = 0; t < NT; ++t) {
        const int c = t & 1;
        const __hip_bfloat16* TA = sA[c];
        const __hip_bfloat16* TB = sB[c];

        bf16x8 aLo[4][2], aHi[4][2], bLo[2][2], bHi[2][2];

        // ================= R0 =================
        #pragma unroll
        for (int m = 0; m < 4; ++m) {
            const int r = wr * 128 + m * 16 + l15;
            aLo[m][0] = FRAG(TA, r, 0);
            aLo[m][1] = FRAG(TA, r, 1);
        }
        #pragma unroll
        for (int n = 0; n < 2; ++n) {
            const int r = wc * 64 + n * 16 + l15;
            bLo[n][0] = FRAG(TB, r, 0);
            bLo[n][1] = FRAG(TB, r, 1);
        }
        __builtin_amdgcn_s_setprio(1);
        #pragma unroll
        for (int k = 0; k < 2; ++k)
            #pragma unroll
            for (int m = 0; m < 4; ++m)
                #pragma unroll
                for (int n = 0; n < 2; ++n)
                    acc[m][n] = __builtin_amdgcn_mfma_f32_16x16x32_bf16(
                                    aLo[m][k], bLo[n][k], acc[m][n], 0, 0, 0);
        __builtin_amdgcn_s_setprio(0);
        if (t + 1 < NT) { STAGE_BG(c ^ 1, t + 1, 2); STAGE_BG(c ^ 1, t + 1, 3); }
        #pragma unroll
        for (int m = 0; m < 4; ++m) {
            const int r = wr * 128 + 64 + m * 16 + l15;
            aHi[m][0] = FRAG(TA, r, 0);
            aHi[m][1] = FRAG(TA, r, 1);
        }
        BAR();   // BAR_A: all A-reads (and bLo) of buf c complete

        // ================= R1 =================
        if (t + 2 < NT) {
            STAGE_AG(c, t + 2, 0); STAGE_AG(c, t + 2, 1);
            STAGE_AG(c, t + 2, 2); STAGE_AG(c, t + 2, 3);
        }
        __builtin_amdgcn_s_setprio(1);
        #pragma unroll
        for (int k = 0; k < 2; ++k)
            #pragma unroll
            for (int m = 0; m < 4; ++m)
                #pragma unroll
                for (int n = 0; n < 2; ++n)
                    acc[4 + m][n] = __builtin_amdgcn_mfma_f32_16x16x32_bf16(
                                    aHi[m][k], bLo[n][k], acc[4 + m][n], 0, 0, 0);
        __builtin_amdgcn_s_setprio(0);
        #pragma unroll
        for (int n = 0; n < 2; ++n) {
            const int r = wc * 64 + 32 + n * 16 + l15;
            bHi[n][0] = FRAG(TB, r, 0);
            bHi[n][1] = FRAG(TB, r, 1);
        }
        BAR();   // BAR_B: all B-reads of buf c complete

        // ================= R2 =================
        if (t + 2 < NT) { STAGE_BG(c, t + 2, 0); STAGE_BG(c, t + 2, 1); }
        __builtin_amdgcn_s_setprio(1);
        #pragma unroll
        for (int k = 0; k < 2; ++k)
            #pragma unroll
            for (int m = 0; m < 4; ++m)
                #pragma unroll
                for (int n = 0; n < 2; ++n)
                    acc[4 + m][2 + n] = __builtin_amdgcn_mfma_f32_16x16x32_bf16(
                                    aHi[m][k], bHi[n][k], acc[4 + m][2 + n], 0, 0, 0);
        #pragma unroll
        for (int k = 0; k < 2; ++k)
            #pragma unroll
            for (int m = 0; m < 4; ++m)
                #pragma unroll
                for (int n = 0; n < 2; ++n)
                    acc[m][2 + n] = __builtin_amdgcn_mfma_f32_16x16x32_bf16(
                                    aLo[m][k], bHi[n][k], acc[m][2 + n], 0, 0, 0);
        __builtin_amdgcn_s_setprio(0);

        // ---------- K-tile boundary ----------
        if (t < NT - 2) {
            VMCNT(6);       // drains all of tile t+1; 6 loads of t+2 in flight
            BAR();
        } else if (t == NT - 2) {
            VMCNT(0);       // tail: drain B(NT-1)g23 (+ leftovers)
            BAR();
        }
        // t == NT-1: registers only; fall through to epilogue
    }

    // ---- epilogue: ReLU + fp32 store ----
    const int row_base = m0 + wr * 128;
    const int col_base = n0 + wc * 64;
    #pragma unroll
    for (int m = 0; m < 8; ++m)
        #pragma unroll
        for (int n = 0; n < 4; ++n) {
            const f32x4 v = acc[m][n];
            const int col = col_base + n * 16 + l15;
            #pragma unroll
            for (int j = 0; j < 4; ++j) {
                const int row = row_base + m * 16 + l4 * 4 + j;
                C[(size_t)row * N_DIM + col] = fmaxf(v[j], 0.0f);
            }
        }
}

// ---------------------------------------------------------------------------
// fp32 fallback GEMM (only if ws_size < 160MB)
// ---------------------------------------------------------------------------
__global__ void gemm_f32_fallback(const float* __restrict__ A,
                                  const float* __restrict__ W,
                                  float* __restrict__ C) {
    __shared__ float As[64][17];
    __shared__ float Bs[64][17];
    const int tx = threadIdx.x & 15, ty = threadIdx.x >> 4;
    const int m0 = blockIdx.y * 64, n0 = blockIdx.x * 64;
    float acc[4][4] = {};
    for (int kt = 0; kt < K_DIM; kt += 16) {
        #pragma unroll
        for (int i = 0; i < 4; ++i) {
            int e = threadIdx.x + i * 256;
            int r = e >> 4, k = e & 15;
            As[r][k] = A[(size_t)(m0 + r) * K_DIM + kt + k];
            Bs[r][k] = W[(size_t)(n0 + r) * K_DIM + kt + k];
        }
        __syncthreads();
        #pragma unroll
        for (int k = 0; k < 16; ++k) {
            float av[4], bv[4];
            #pragma unroll
            for (int i = 0; i < 4; ++i) av[i] = As[ty * 4 + i][k];
            #pragma unroll
            for (int i = 0; i < 4; ++i) bv[i] = Bs[tx * 4 + i][k];
            #pragma unroll
            for (int i = 0; i < 4; ++i)
                #pragma unroll
                for (int j = 0; j < 4; ++j) acc[i][j] += av[i] * bv[j];
        }
        __syncthreads();
    }
    #pragma unroll
    for (int i = 0; i < 4; ++i)
        #pragma unroll
        for (int j = 0; j < 4; ++j)
            C[(size_t)(m0 + ty * 4 + i) * N_DIM + n0 + tx * 4 + j] =
                fmaxf(acc[i][j], 0.0f);
}

extern "C" void kernel_launch(void* const* d_in, const int* in_sizes, int n_in,
                              void* d_out, int out_size, void* d_ws, size_t ws_size,
                              hipStream_t stream) {
    const float* x       = (const float*)d_in[0];
    const int*   indices = (const int*)d_in[1];
    const float* values  = (const float*)d_in[2];
    float*       out     = (float*)d_out;

    float* Wf = (float*)((char*)d_ws + WF32_OFF);

    // 1. zero + scatter-build W (fp32, duplicates accumulate)
    hipMemsetAsync(Wf, 0, (size_t)N_DIM * K_DIM * sizeof(float), stream);
    scatter_kernel<<<(NNZ + 255) / 256, 256, 0, stream>>>(indices, values, Wf);

    if (ws_size >= WS_NEED) {
        unsigned short* Wb = (unsigned short*)((char*)d_ws + WBF16_OFF);
        unsigned short* xb = (unsigned short*)((char*)d_ws + XB_OFF);

        // 2. fused fp32 -> bf16 conversion (W then x)
        const int n4W = (N_DIM * K_DIM) / 4;
        const int n4T = n4W + (M_DIM * K_DIM) / 4;
        convert_both_kernel<<<(n4T + 255) / 256, 256, 0, stream>>>(
            Wf, x, Wb, xb, n4W, n4T);

        // 3. 256^2 3-barrier bf16 MFMA GEMM + ReLU
        gemm256_v8<<<(M_DIM / 256) * (N_DIM / 256), 512, 0, stream>>>(
            (const __hip_bfloat16*)xb, (const __hip_bfloat16*)Wb, out);
    } else {
        gemm_f32_fallback<<<dim3(N_DIM / 64, M_DIM / 64), 256, 0, stream>>>(
            x, Wf, out);
    }
}